// Round 6
// baseline (100.056 us; speedup 1.0000x reference)
//
#include <hip/hip_runtime.h>
#include <math.h>

#define HN 1024
#define VN 50257
#define SN 8192

// ws layout (float offsets)
#define WS_PARTIAL 0          // 256*1024: per-rowchunk column partial sums
#define WS_AA      262144     // 1024: attn_applied (column mean)
#define WS_X       263168     // 1024: relu(combined)
#define WS_GH      264192     // 3072: raw w_hh @ h0
#define WS_CEMB    267264     // 1024: comb_w[:, :H] @ emb + comb_b
#define WS_HNEW    270336     // 1024: h_new
#define WS_LOGITS  271360     // 50257
#define WS_EXPD    321618     // 2112 doubles (8B-aligned: 321618*4 % 8 == 0)
#define WS_CNT     326100     // 1 int: spin-barrier counter (zeroed by k2)

__device__ __forceinline__ float wred(float v) {
#pragma unroll
  for (int m = 32; m; m >>= 1) v += __shfl_xor(v, m);
  return v;
}

__device__ __forceinline__ float dot4(float4 a, float4 b) {
  return a.x * b.x + a.y * b.y + a.z * b.z + a.w * b.w;
}

// K1 (384 blocks x 1024 thr), block-specialized, ~8KB per wave everywhere:
//   blk<256  : enc column partials (32 rows/blk, LDS reduce) + attn_weights out
//   256..351 : gh = w_hh @ h0, 2 rows per wave (1536 waves)
//   352..383 : c_emb = comb_w[:, :H] @ emb + comb_b, 2 rows per wave (512 waves)
__global__ __launch_bounds__(1024) void k1_front(
    const float* __restrict__ enc, const float* __restrict__ w_hh,
    const float* __restrict__ hidden, const int* __restrict__ token,
    const float* __restrict__ embedding, const float* __restrict__ comb_w,
    const float* __restrict__ comb_b, float* __restrict__ ws,
    float* __restrict__ out_attn) {
  const int blk = blockIdx.x, t = threadIdx.x;
  if (blk < 256) {
    __shared__ float4 lds[1024];
    const int g = t >> 8, c4 = t & 255;
    const float4* e4 = (const float4*)enc + ((size_t)blk * 32 + g * 8) * 256 + c4;
    float4 acc = make_float4(0.f, 0.f, 0.f, 0.f);
#pragma unroll
    for (int r = 0; r < 8; ++r) {
      float4 v = e4[r * 256];
      acc.x += v.x; acc.y += v.y; acc.z += v.z; acc.w += v.w;
    }
    lds[t] = acc;
    __syncthreads();
    if (t < 256) {
      float4 a = lds[t], b = lds[t + 256], c = lds[t + 512], d = lds[t + 768];
      float4 s = make_float4(a.x + b.x + c.x + d.x, a.y + b.y + c.y + d.y,
                             a.z + b.z + c.z + d.z, a.w + b.w + c.w + d.w);
      ((float4*)(ws + WS_PARTIAL))[blk * 256 + t] = s;
    }
    if (t < 32) out_attn[blk * 32 + t] = 1.f / 8192.f;  // softmax(const) exact
  } else if (blk < 352) {
    const int wg = (blk - 256) * 16 + (t >> 6);  // 0..1535
    const int l = t & 63;
    const float4* h4 = (const float4*)hidden;
    float4 hv0 = h4[l], hv1 = h4[64 + l], hv2 = h4[128 + l], hv3 = h4[192 + l];
#pragma unroll
    for (int k = 0; k < 2; ++k) {
      const int r = wg + k * 1536;  // 0..3071
      const float4* m4 = (const float4*)w_hh + (size_t)r * 256;
      float acc = dot4(m4[l], hv0) + dot4(m4[64 + l], hv1) +
                  dot4(m4[128 + l], hv2) + dot4(m4[192 + l], hv3);
      acc = wred(acc);
      if (l == 0) ws[WS_GH + r] = acc;
    }
  } else {
    const int iw = (blk - 352) * 16 + (t >> 6);  // 0..511
    const int l = t & 63;
    const int tok = token[0];
    const float4* emb4 = (const float4*)embedding + (size_t)tok * 256;
#pragma unroll
    for (int k = 0; k < 2; ++k) {
      const int i = iw + k * 512;  // 0..1023
      const float4* cw4 = (const float4*)comb_w + (size_t)i * 512;  // first half
      float acc = dot4(cw4[l], emb4[l]) + dot4(cw4[64 + l], emb4[64 + l]) +
                  dot4(cw4[128 + l], emb4[128 + l]) + dot4(cw4[192 + l], emb4[192 + l]);
      acc = wred(acc);
      if (l == 0) ws[WS_CEMB + i] = acc + comb_b[i];
    }
  }
}

// K2 (32 blocks x 1024): reduce 256 rowchunk partials -> attn_applied.
// Thread: col c = b*32 + (t&31), rowgroup rg = t>>5 sums 8 rows; LDS reduce.
// Block 0 also zeroes the k34 spin counter.
__global__ __launch_bounds__(1024) void k2_reduce(float* __restrict__ ws) {
  __shared__ float lds[1024];
  const int t = threadIdx.x, b = blockIdx.x;
  if (b == 0 && t == 0) ((int*)ws)[WS_CNT] = 0;
  const int c = b * 32 + (t & 31), rg = t >> 5;
  const float* p = ws + WS_PARTIAL;
  float s = 0.f;
#pragma unroll
  for (int j = 0; j < 8; ++j) s += p[(rg * 8 + j) * 1024 + c];
  lds[t] = s;
  __syncthreads();
  if (t < 32) {
    float a = 0.f;
#pragma unroll
    for (int j = 0; j < 32; ++j) a += lds[j * 32 + t];
    ws[WS_AA + b * 32 + t] = a * (1.f / 8192.f);
  }
}

// K34 (256 blocks x 256): x-phase (wave per row: x = relu(cemb + cw2@aa)),
// device-scope spin barrier, then gates-phase (wave computes 3 gi rows + GRU).
// All 256 blocks (1024 waves, no LDS) are trivially co-resident -> no deadlock.
__global__ void k34_x_gates(const float* __restrict__ comb_w,
                            const float* __restrict__ w_ih,
                            const float* __restrict__ b_ih, const float* __restrict__ b_hh,
                            const float* __restrict__ hidden, float* __restrict__ ws,
                            float* __restrict__ d_out) {
  const int w = threadIdx.x >> 6, l = threadIdx.x & 63;
  const int i = blockIdx.x * 4 + w;  // 0..1023
  // --- x phase ---
  {
    const float4* aa4 = (const float4*)(ws + WS_AA);
    const float4* cw4 = (const float4*)comb_w + (size_t)i * 512 + 256;  // 2nd half
    float acc = dot4(cw4[l], aa4[l]) + dot4(cw4[64 + l], aa4[64 + l]) +
                dot4(cw4[128 + l], aa4[128 + l]) + dot4(cw4[192 + l], aa4[192 + l]);
    acc = wred(acc);
    if (l == 0) ws[WS_X + i] = fmaxf(ws[WS_CEMB + i] + acc, 0.f);
  }
  // --- barrier: all blocks' x visible ---
  __threadfence();
  __syncthreads();
  int* cnt = (int*)ws + WS_CNT;
  if (threadIdx.x == 0) {
    __atomic_fetch_add(cnt, 1, __ATOMIC_ACQ_REL);
    while (__hip_atomic_load(cnt, __ATOMIC_ACQUIRE, __HIP_MEMORY_SCOPE_AGENT) < 256) {
    }
  }
  __syncthreads();
  __threadfence();
  // --- gates phase ---
  const float4* x4 = (const float4*)(ws + WS_X);
  float4 xv0 = x4[l], xv1 = x4[64 + l], xv2 = x4[128 + l], xv3 = x4[192 + l];
  const float4* m0 = (const float4*)w_ih + (size_t)i * 256;
  const float4* m1 = (const float4*)w_ih + (size_t)(i + 1024) * 256;
  const float4* m2 = (const float4*)w_ih + (size_t)(i + 2048) * 256;
  float a0 = dot4(m0[l], xv0) + dot4(m0[64 + l], xv1) +
             dot4(m0[128 + l], xv2) + dot4(m0[192 + l], xv3);
  float a1 = dot4(m1[l], xv0) + dot4(m1[64 + l], xv1) +
             dot4(m1[128 + l], xv2) + dot4(m1[192 + l], xv3);
  float a2 = dot4(m2[l], xv0) + dot4(m2[64 + l], xv1) +
             dot4(m2[128 + l], xv2) + dot4(m2[192 + l], xv3);
  a0 = wred(a0); a1 = wred(a1); a2 = wred(a2);
  if (l == 0) {
    float ir = a0 + b_ih[i];
    float iz = a1 + b_ih[i + 1024];
    float inn = a2 + b_ih[i + 2048];
    float hr = ws[WS_GH + i] + b_hh[i];
    float hz = ws[WS_GH + i + 1024] + b_hh[i + 1024];
    float hn = ws[WS_GH + i + 2048] + b_hh[i + 2048];
    float rg = 1.f / (1.f + expf(-(ir + hr)));
    float zg = 1.f / (1.f + expf(-(iz + hz)));
    float ng = tanhf(inn + rg * hn);
    float h = (1.f - zg) * ng + zg * hidden[i];
    ws[WS_HNEW + i] = h;
    d_out[VN + i] = h;  // h_new output region
  }
}

// K5 (2112 blocks x 256 = 8448 waves): logits GEMV, 2-row ILP, every wave
// <= 6 rows (balanced). Per-block exp partials in fixed order (deterministic).
__global__ void k5_logits(const float* __restrict__ out_w, const float* __restrict__ out_b,
                          float* __restrict__ ws) {
  const int blk = blockIdx.x, t = threadIdx.x;
  const int w = t >> 6, l = t & 63;
  const int gw = blk * 4 + w;  // 0..8447
  __shared__ float4 hs4[256];
  __shared__ double sd[4];
  hs4[t] = ((const float4*)(ws + WS_HNEW))[t];
  __syncthreads();
  float4 h0_ = hs4[l], h1_ = hs4[64 + l], h2_ = hs4[128 + l], h3_ = hs4[192 + l];
  const float4* ow4 = (const float4*)out_w;
  double eacc = 0.0;
#pragma unroll
  for (int it = 0; it < 3; ++it) {
    const int v0 = gw + it * 16896;        // always < VN (max 42239)
    const int v1 = v0 + 8448;
    const bool ok1 = (v1 < VN);            // wave-uniform
    const float4* r0 = ow4 + (size_t)v0 * 256;
    const float4* r1 = ow4 + (size_t)(ok1 ? v1 : v0) * 256;  // clamp: in-bounds
    float a0 = dot4(r0[l], h0_) + dot4(r0[64 + l], h1_) +
               dot4(r0[128 + l], h2_) + dot4(r0[192 + l], h3_);
    float a1 = dot4(r1[l], h0_) + dot4(r1[64 + l], h1_) +
               dot4(r1[128 + l], h2_) + dot4(r1[192 + l], h3_);
    a0 = wred(a0);
    a1 = wred(a1);
    if (l == 0) {
      float lg0 = a0 + out_b[v0];
      ws[WS_LOGITS + v0] = lg0;
      eacc += (double)expf(lg0);  // |logit| small: no max-subtract needed
      if (ok1) {
        float lg1 = a1 + out_b[v1];
        ws[WS_LOGITS + v1] = lg1;
        eacc += (double)expf(lg1);
      }
    }
  }
  if (l == 0) sd[w] = eacc;
  __syncthreads();
  if (t == 0) ((double*)(ws + WS_EXPD))[blk] = sd[0] + sd[1] + sd[2] + sd[3];
}

// K6: redundant deterministic logZ (fixed-order reduce of 2112 doubles) + subtract
__global__ void k6_final(const float* __restrict__ ws, float* __restrict__ d_out) {
  __shared__ double sd[256];
  const int t = threadIdx.x;
  const double* ed = (const double*)(ws + WS_EXPD);
  double a = 0.0;
#pragma unroll
  for (int j = 0; j < 8; ++j) a += ed[t + j * 256];
  if (t < 64) a += ed[t + 2048];
  sd[t] = a;
  __syncthreads();
  for (int s = 128; s; s >>= 1) {
    if (t < s) sd[t] += sd[t + s];
    __syncthreads();
  }
  const float logZ = (float)log(sd[0]);
  const int v = blockIdx.x * 256 + t;
  if (v < VN) d_out[v] = ws[WS_LOGITS + v] - logZ;
}

extern "C" void kernel_launch(void* const* d_in, const int* in_sizes, int n_in,
                              void* d_out, int out_size, void* d_ws, size_t ws_size,
                              hipStream_t stream) {
  const int* token = (const int*)d_in[0];
  const float* hidden = (const float*)d_in[1];
  const float* enc = (const float*)d_in[2];
  const float* embedding = (const float*)d_in[3];
  // d_in[4] attn_w, d_in[5] attn_b unused: softmax(broadcast(scalar)) is uniform
  const float* comb_w = (const float*)d_in[6];
  const float* comb_b = (const float*)d_in[7];
  const float* w_ih = (const float*)d_in[8];
  const float* w_hh = (const float*)d_in[9];
  const float* b_ih = (const float*)d_in[10];
  const float* b_hh = (const float*)d_in[11];
  const float* out_w = (const float*)d_in[12];
  const float* out_b = (const float*)d_in[13];
  float* out = (float*)d_out;
  float* ws = (float*)d_ws;

  k1_front<<<384, 1024, 0, stream>>>(enc, w_hh, hidden, token, embedding,
                                     comb_w, comb_b, ws, out + VN + HN);
  k2_reduce<<<32, 1024, 0, stream>>>(ws);
  k34_x_gates<<<256, 256, 0, stream>>>(comb_w, w_ih, b_ih, b_hh, hidden, ws, out);
  k5_logits<<<2112, 256, 0, stream>>>(out_w, out_b, ws);
  k6_final<<<197, 256, 0, stream>>>(ws, out);
}

// Round 7
// 60.162 us; speedup vs baseline: 1.6631x; 1.6631x over previous
//
#include <hip/hip_runtime.h>
#include <math.h>

#define HN 1024
#define VN 50257
#define SN 8192

// ws layout (float offsets)
#define WS_PARTIAL 0          // 256*1024: per-rowchunk column partial sums
#define WS_AA      262144     // 1024: attn_applied (column mean)
#define WS_X       263168     // 1024: relu(combined)
#define WS_GH      264192     // 3072: raw w_hh @ h0
#define WS_CEMB    267264     // 1024: comb_w[:, :H] @ emb + comb_b
#define WS_HNEW    270336     // 1024: h_new
#define WS_LOGITS  271360     // 50257
#define WS_EXPD    321618     // 2112 doubles (8B-aligned: 321618*4 % 8 == 0)

__device__ __forceinline__ float wred(float v) {
#pragma unroll
  for (int m = 32; m; m >>= 1) v += __shfl_xor(v, m);
  return v;
}

__device__ __forceinline__ float dot4(float4 a, float4 b) {
  return a.x * b.x + a.y * b.y + a.z * b.z + a.w * b.w;
}

// K1 (384 blocks x 1024 thr), block-specialized, ~8KB per wave everywhere:
//   blk<256  : enc column partials (32 rows/blk, LDS reduce) + attn_weights out
//   256..351 : gh = w_hh @ h0, 2 rows per wave (1536 waves)
//   352..383 : c_emb = comb_w[:, :H] @ emb + comb_b, 2 rows per wave (512 waves)
__global__ __launch_bounds__(1024) void k1_front(
    const float* __restrict__ enc, const float* __restrict__ w_hh,
    const float* __restrict__ hidden, const int* __restrict__ token,
    const float* __restrict__ embedding, const float* __restrict__ comb_w,
    const float* __restrict__ comb_b, float* __restrict__ ws,
    float* __restrict__ out_attn) {
  const int blk = blockIdx.x, t = threadIdx.x;
  if (blk < 256) {
    __shared__ float4 lds[1024];
    const int g = t >> 8, c4 = t & 255;
    const float4* e4 = (const float4*)enc + ((size_t)blk * 32 + g * 8) * 256 + c4;
    float4 acc = make_float4(0.f, 0.f, 0.f, 0.f);
#pragma unroll
    for (int r = 0; r < 8; ++r) {
      float4 v = e4[r * 256];
      acc.x += v.x; acc.y += v.y; acc.z += v.z; acc.w += v.w;
    }
    lds[t] = acc;
    __syncthreads();
    if (t < 256) {
      float4 a = lds[t], b = lds[t + 256], c = lds[t + 512], d = lds[t + 768];
      float4 s = make_float4(a.x + b.x + c.x + d.x, a.y + b.y + c.y + d.y,
                             a.z + b.z + c.z + d.z, a.w + b.w + c.w + d.w);
      ((float4*)(ws + WS_PARTIAL))[blk * 256 + t] = s;
    }
    if (t < 32) out_attn[blk * 32 + t] = 1.f / 8192.f;  // softmax(const) exact
  } else if (blk < 352) {
    const int wg = (blk - 256) * 16 + (t >> 6);  // 0..1535
    const int l = t & 63;
    const float4* h4 = (const float4*)hidden;
    float4 hv0 = h4[l], hv1 = h4[64 + l], hv2 = h4[128 + l], hv3 = h4[192 + l];
#pragma unroll
    for (int k = 0; k < 2; ++k) {
      const int r = wg + k * 1536;  // 0..3071
      const float4* m4 = (const float4*)w_hh + (size_t)r * 256;
      float acc = dot4(m4[l], hv0) + dot4(m4[64 + l], hv1) +
                  dot4(m4[128 + l], hv2) + dot4(m4[192 + l], hv3);
      acc = wred(acc);
      if (l == 0) ws[WS_GH + r] = acc;
    }
  } else {
    const int iw = (blk - 352) * 16 + (t >> 6);  // 0..511
    const int l = t & 63;
    const int tok = token[0];
    const float4* emb4 = (const float4*)embedding + (size_t)tok * 256;
#pragma unroll
    for (int k = 0; k < 2; ++k) {
      const int i = iw + k * 512;  // 0..1023
      const float4* cw4 = (const float4*)comb_w + (size_t)i * 512;  // first half
      float acc = dot4(cw4[l], emb4[l]) + dot4(cw4[64 + l], emb4[64 + l]) +
                  dot4(cw4[128 + l], emb4[128 + l]) + dot4(cw4[192 + l], emb4[192 + l]);
      acc = wred(acc);
      if (l == 0) ws[WS_CEMB + i] = acc + comb_b[i];
    }
  }
}

// K2 (32 blocks x 1024): reduce 256 rowchunk partials -> attn_applied.
// Thread: col c = b*32 + (t&31), rowgroup rg = t>>5 sums 8 rows; LDS reduce.
__global__ __launch_bounds__(1024) void k2_reduce(float* __restrict__ ws) {
  __shared__ float lds[1024];
  const int t = threadIdx.x, b = blockIdx.x;
  const int c = b * 32 + (t & 31), rg = t >> 5;
  const float* p = ws + WS_PARTIAL;
  float s = 0.f;
#pragma unroll
  for (int j = 0; j < 8; ++j) s += p[(rg * 8 + j) * 1024 + c];
  lds[t] = s;
  __syncthreads();
  if (t < 32) {
    float a = 0.f;
#pragma unroll
    for (int j = 0; j < 32; ++j) a += lds[j * 32 + t];
    ws[WS_AA + b * 32 + t] = a * (1.f / 8192.f);
  }
}

// K3 (256 blocks x 256): x = relu(c_emb + comb_w[:, H:] @ aa); wave per row
__global__ void k3_x(const float* __restrict__ comb_w, float* __restrict__ ws) {
  const int w = threadIdx.x >> 6, l = threadIdx.x & 63;
  const int i = blockIdx.x * 4 + w;  // 0..1023
  const float4* aa4 = (const float4*)(ws + WS_AA);
  const float4* cw4 = (const float4*)comb_w + (size_t)i * 512 + 256;  // second half
  float acc = dot4(cw4[l], aa4[l]) + dot4(cw4[64 + l], aa4[64 + l]) +
              dot4(cw4[128 + l], aa4[128 + l]) + dot4(cw4[192 + l], aa4[192 + l]);
  acc = wred(acc);
  if (l == 0) ws[WS_X + i] = fmaxf(ws[WS_CEMB + i] + acc, 0.f);
}

// K4 (256 blocks x 256): wave computes all 3 gi rows for its i, then lane 0
// applies GRU gate math -> h_new. No gi round-trip, no separate h kernel.
__global__ void k4_gates_h(const float* __restrict__ w_ih,
                           const float* __restrict__ b_ih, const float* __restrict__ b_hh,
                           const float* __restrict__ hidden, float* __restrict__ ws,
                           float* __restrict__ d_out) {
  const int w = threadIdx.x >> 6, l = threadIdx.x & 63;
  const int i = blockIdx.x * 4 + w;  // 0..1023
  const float4* x4 = (const float4*)(ws + WS_X);
  float4 xv0 = x4[l], xv1 = x4[64 + l], xv2 = x4[128 + l], xv3 = x4[192 + l];
  const float4* m0 = (const float4*)w_ih + (size_t)i * 256;
  const float4* m1 = (const float4*)w_ih + (size_t)(i + 1024) * 256;
  const float4* m2 = (const float4*)w_ih + (size_t)(i + 2048) * 256;
  float a0 = dot4(m0[l], xv0) + dot4(m0[64 + l], xv1) +
             dot4(m0[128 + l], xv2) + dot4(m0[192 + l], xv3);
  float a1 = dot4(m1[l], xv0) + dot4(m1[64 + l], xv1) +
             dot4(m1[128 + l], xv2) + dot4(m1[192 + l], xv3);
  float a2 = dot4(m2[l], xv0) + dot4(m2[64 + l], xv1) +
             dot4(m2[128 + l], xv2) + dot4(m2[192 + l], xv3);
  a0 = wred(a0); a1 = wred(a1); a2 = wred(a2);
  if (l == 0) {
    float ir = a0 + b_ih[i];
    float iz = a1 + b_ih[i + 1024];
    float inn = a2 + b_ih[i + 2048];
    float hr = ws[WS_GH + i] + b_hh[i];
    float hz = ws[WS_GH + i + 1024] + b_hh[i + 1024];
    float hn = ws[WS_GH + i + 2048] + b_hh[i + 2048];
    float rg = 1.f / (1.f + expf(-(ir + hr)));
    float zg = 1.f / (1.f + expf(-(iz + hz)));
    float ng = tanhf(inn + rg * hn);
    float h = (1.f - zg) * ng + zg * hidden[i];
    ws[WS_HNEW + i] = h;
    d_out[VN + i] = h;  // h_new output region
  }
}

// K5 (2112 blocks x 256 = 8448 waves): logits GEMV, 2-row ILP, every wave
// <= 6 rows (balanced). Per-block exp partials in fixed order (deterministic).
__global__ void k5_logits(const float* __restrict__ out_w, const float* __restrict__ out_b,
                          float* __restrict__ ws) {
  const int blk = blockIdx.x, t = threadIdx.x;
  const int w = t >> 6, l = t & 63;
  const int gw = blk * 4 + w;  // 0..8447
  __shared__ float4 hs4[256];
  __shared__ double sd[4];
  hs4[t] = ((const float4*)(ws + WS_HNEW))[t];
  __syncthreads();
  float4 h0_ = hs4[l], h1_ = hs4[64 + l], h2_ = hs4[128 + l], h3_ = hs4[192 + l];
  const float4* ow4 = (const float4*)out_w;
  double eacc = 0.0;
#pragma unroll
  for (int it = 0; it < 3; ++it) {
    const int v0 = gw + it * 16896;        // always < VN (max 42239)
    const int v1 = v0 + 8448;
    const bool ok1 = (v1 < VN);            // wave-uniform
    const float4* r0 = ow4 + (size_t)v0 * 256;
    const float4* r1 = ow4 + (size_t)(ok1 ? v1 : v0) * 256;  // clamp: in-bounds
    float a0 = dot4(r0[l], h0_) + dot4(r0[64 + l], h1_) +
               dot4(r0[128 + l], h2_) + dot4(r0[192 + l], h3_);
    float a1 = dot4(r1[l], h0_) + dot4(r1[64 + l], h1_) +
               dot4(r1[128 + l], h2_) + dot4(r1[192 + l], h3_);
    a0 = wred(a0);
    a1 = wred(a1);
    if (l == 0) {
      float lg0 = a0 + out_b[v0];
      ws[WS_LOGITS + v0] = lg0;
      eacc += (double)expf(lg0);  // |logit| small: no max-subtract needed
      if (ok1) {
        float lg1 = a1 + out_b[v1];
        ws[WS_LOGITS + v1] = lg1;
        eacc += (double)expf(lg1);
      }
    }
  }
  if (l == 0) sd[w] = eacc;
  __syncthreads();
  if (t == 0) ((double*)(ws + WS_EXPD))[blk] = sd[0] + sd[1] + sd[2] + sd[3];
}

// K6: redundant deterministic logZ (fixed-order reduce of 2112 doubles) + subtract
__global__ void k6_final(const float* __restrict__ ws, float* __restrict__ d_out) {
  __shared__ double sd[256];
  const int t = threadIdx.x;
  const double* ed = (const double*)(ws + WS_EXPD);
  double a = 0.0;
#pragma unroll
  for (int j = 0; j < 8; ++j) a += ed[t + j * 256];
  if (t < 64) a += ed[t + 2048];
  sd[t] = a;
  __syncthreads();
  for (int s = 128; s; s >>= 1) {
    if (t < s) sd[t] += sd[t + s];
    __syncthreads();
  }
  const float logZ = (float)log(sd[0]);
  const int v = blockIdx.x * 256 + t;
  if (v < VN) d_out[v] = ws[WS_LOGITS + v] - logZ;
}

extern "C" void kernel_launch(void* const* d_in, const int* in_sizes, int n_in,
                              void* d_out, int out_size, void* d_ws, size_t ws_size,
                              hipStream_t stream) {
  const int* token = (const int*)d_in[0];
  const float* hidden = (const float*)d_in[1];
  const float* enc = (const float*)d_in[2];
  const float* embedding = (const float*)d_in[3];
  // d_in[4] attn_w, d_in[5] attn_b unused: softmax(broadcast(scalar)) is uniform
  const float* comb_w = (const float*)d_in[6];
  const float* comb_b = (const float*)d_in[7];
  const float* w_ih = (const float*)d_in[8];
  const float* w_hh = (const float*)d_in[9];
  const float* b_ih = (const float*)d_in[10];
  const float* b_hh = (const float*)d_in[11];
  const float* out_w = (const float*)d_in[12];
  const float* out_b = (const float*)d_in[13];
  float* out = (float*)d_out;
  float* ws = (float*)d_ws;

  k1_front<<<384, 1024, 0, stream>>>(enc, w_hh, hidden, token, embedding,
                                     comb_w, comb_b, ws, out + VN + HN);
  k2_reduce<<<32, 1024, 0, stream>>>(ws);
  k3_x<<<256, 256, 0, stream>>>(comb_w, ws);
  k4_gates_h<<<256, 256, 0, stream>>>(w_ih, b_ih, b_hh, hidden, ws, out);
  k5_logits<<<2112, 256, 0, stream>>>(out_w, out_b, ws);
  k6_final<<<197, 256, 0, stream>>>(ws, out);
}

// Round 8
// 58.156 us; speedup vs baseline: 1.7205x; 1.0345x over previous
//
#include <hip/hip_runtime.h>
#include <math.h>

#define HN 1024
#define VN 50257
#define SN 8192

// ws layout (float offsets)
#define WS_PARTIAL 0          // 256*1024: per-rowchunk column partial sums
#define WS_AA      262144     // 1024: attn_applied (column mean)
#define WS_X       263168     // 1024: relu(combined)
#define WS_GH      264192     // 3072: raw w_hh @ h0
#define WS_CEMB    267264     // 1024: comb_w[:, :H] @ emb + comb_b
#define WS_HNEW    270336     // 1024: h_new
#define WS_LOGITS  271360     // 50257
#define WS_EXPD    321618     // 2112 doubles (8B-aligned: 321618*4 % 8 == 0)

__device__ __forceinline__ float wred(float v) {
#pragma unroll
  for (int m = 32; m; m >>= 1) v += __shfl_xor(v, m);
  return v;
}

__device__ __forceinline__ float dot4(float4 a, float4 b) {
  return a.x * b.x + a.y * b.y + a.z * b.z + a.w * b.w;
}

// K1 (256 blocks x 1024 thr), perfectly uniform load (~184 KB/block):
//   phase A: 32-row enc column partial (4 rowgroups x 256 cols, LDS reduce)
//            + 32 attn_weights elements
//   phase B: wave w<12 -> gh row blk*12+w; w>=12 -> cemb row blk*4+(w-12)
__global__ __launch_bounds__(1024) void k1_front(
    const float* __restrict__ enc, const float* __restrict__ w_hh,
    const float* __restrict__ hidden, const int* __restrict__ token,
    const float* __restrict__ embedding, const float* __restrict__ comb_w,
    const float* __restrict__ comb_b, float* __restrict__ ws,
    float* __restrict__ out_attn) {
  const int blk = blockIdx.x, t = threadIdx.x;
  __shared__ float4 lds[1024];
  // --- phase A: enc column partials ---
  {
    const int g = t >> 8, c4 = t & 255;
    const float4* e4 = (const float4*)enc + ((size_t)blk * 32 + g * 8) * 256 + c4;
    float4 acc = make_float4(0.f, 0.f, 0.f, 0.f);
#pragma unroll
    for (int r = 0; r < 8; ++r) {
      float4 v = e4[r * 256];
      acc.x += v.x; acc.y += v.y; acc.z += v.z; acc.w += v.w;
    }
    lds[t] = acc;
  }
  __syncthreads();
  if (t < 256) {
    float4 a = lds[t], b = lds[t + 256], c = lds[t + 512], d = lds[t + 768];
    float4 s = make_float4(a.x + b.x + c.x + d.x, a.y + b.y + c.y + d.y,
                           a.z + b.z + c.z + d.z, a.w + b.w + c.w + d.w);
    ((float4*)(ws + WS_PARTIAL))[blk * 256 + t] = s;
  }
  if (t < 32) out_attn[blk * 32 + t] = 1.f / 8192.f;  // softmax(const) exact
  // --- phase B: one GEMV row per wave ---
  const int w = t >> 6, l = t & 63;
  if (w < 12) {
    const int r = blk * 12 + w;  // 0..3071
    const float4* h4 = (const float4*)hidden;
    const float4* m4 = (const float4*)w_hh + (size_t)r * 256;
    float acc = dot4(m4[l], h4[l]) + dot4(m4[64 + l], h4[64 + l]) +
                dot4(m4[128 + l], h4[128 + l]) + dot4(m4[192 + l], h4[192 + l]);
    acc = wred(acc);
    if (l == 0) ws[WS_GH + r] = acc;
  } else {
    const int i = blk * 4 + (w - 12);  // 0..1023
    const int tok = token[0];
    const float4* emb4 = (const float4*)embedding + (size_t)tok * 256;
    const float4* cw4 = (const float4*)comb_w + (size_t)i * 512;  // first half
    float acc = dot4(cw4[l], emb4[l]) + dot4(cw4[64 + l], emb4[64 + l]) +
                dot4(cw4[128 + l], emb4[128 + l]) + dot4(cw4[192 + l], emb4[192 + l]);
    acc = wred(acc);
    if (l == 0) ws[WS_CEMB + i] = acc + comb_b[i];
  }
}

// K2 (32 blocks x 1024): reduce 256 rowchunk partials -> attn_applied.
__global__ __launch_bounds__(1024) void k2_reduce(float* __restrict__ ws) {
  __shared__ float lds[1024];
  const int t = threadIdx.x, b = blockIdx.x;
  const int c = b * 32 + (t & 31), rg = t >> 5;
  const float* p = ws + WS_PARTIAL;
  float s = 0.f;
#pragma unroll
  for (int j = 0; j < 8; ++j) s += p[(rg * 8 + j) * 1024 + c];
  lds[t] = s;
  __syncthreads();
  if (t < 32) {
    float a = 0.f;
#pragma unroll
    for (int j = 0; j < 32; ++j) a += lds[j * 32 + t];
    ws[WS_AA + b * 32 + t] = a * (1.f / 8192.f);
  }
}

// K3 (256 blocks x 256): x = relu(c_emb + comb_w[:, H:] @ aa); wave per row
__global__ void k3_x(const float* __restrict__ comb_w, float* __restrict__ ws) {
  const int w = threadIdx.x >> 6, l = threadIdx.x & 63;
  const int i = blockIdx.x * 4 + w;  // 0..1023
  const float4* aa4 = (const float4*)(ws + WS_AA);
  const float4* cw4 = (const float4*)comb_w + (size_t)i * 512 + 256;  // second half
  float acc = dot4(cw4[l], aa4[l]) + dot4(cw4[64 + l], aa4[64 + l]) +
              dot4(cw4[128 + l], aa4[128 + l]) + dot4(cw4[192 + l], aa4[192 + l]);
  acc = wred(acc);
  if (l == 0) ws[WS_X + i] = fmaxf(ws[WS_CEMB + i] + acc, 0.f);
}

// K4 (256 blocks x 256): wave computes all 3 gi rows for its i, then lane 0
// applies GRU gate math -> h_new.
__global__ void k4_gates_h(const float* __restrict__ w_ih,
                           const float* __restrict__ b_ih, const float* __restrict__ b_hh,
                           const float* __restrict__ hidden, float* __restrict__ ws,
                           float* __restrict__ d_out) {
  const int w = threadIdx.x >> 6, l = threadIdx.x & 63;
  const int i = blockIdx.x * 4 + w;  // 0..1023
  const float4* x4 = (const float4*)(ws + WS_X);
  float4 xv0 = x4[l], xv1 = x4[64 + l], xv2 = x4[128 + l], xv3 = x4[192 + l];
  const float4* m0 = (const float4*)w_ih + (size_t)i * 256;
  const float4* m1 = (const float4*)w_ih + (size_t)(i + 1024) * 256;
  const float4* m2 = (const float4*)w_ih + (size_t)(i + 2048) * 256;
  float a0 = dot4(m0[l], xv0) + dot4(m0[64 + l], xv1) +
             dot4(m0[128 + l], xv2) + dot4(m0[192 + l], xv3);
  float a1 = dot4(m1[l], xv0) + dot4(m1[64 + l], xv1) +
             dot4(m1[128 + l], xv2) + dot4(m1[192 + l], xv3);
  float a2 = dot4(m2[l], xv0) + dot4(m2[64 + l], xv1) +
             dot4(m2[128 + l], xv2) + dot4(m2[192 + l], xv3);
  a0 = wred(a0); a1 = wred(a1); a2 = wred(a2);
  if (l == 0) {
    float ir = a0 + b_ih[i];
    float iz = a1 + b_ih[i + 1024];
    float inn = a2 + b_ih[i + 2048];
    float hr = ws[WS_GH + i] + b_hh[i];
    float hz = ws[WS_GH + i + 1024] + b_hh[i + 1024];
    float hn = ws[WS_GH + i + 2048] + b_hh[i + 2048];
    float rg = 1.f / (1.f + expf(-(ir + hr)));
    float zg = 1.f / (1.f + expf(-(iz + hz)));
    float ng = tanhf(inn + rg * hn);
    float h = (1.f - zg) * ng + zg * hidden[i];
    ws[WS_HNEW + i] = h;
    d_out[VN + i] = h;  // h_new output region
  }
}

// K5 (2112 blocks x 256 = 8448 waves): logits GEMV, 2 iters x 3-row ILP,
// every wave <= 6 rows. h_new read direct from global (L1-cached per CU).
__global__ void k5_logits(const float* __restrict__ out_w, const float* __restrict__ out_b,
                          float* __restrict__ ws) {
  const int blk = blockIdx.x, t = threadIdx.x;
  const int w = t >> 6, l = t & 63;
  const int gw = blk * 4 + w;  // 0..8447
  const float4* h4p = (const float4*)(ws + WS_HNEW);
  float4 h0_ = h4p[l], h1_ = h4p[64 + l], h2_ = h4p[128 + l], h3_ = h4p[192 + l];
  const float4* ow4 = (const float4*)out_w;
  double eacc = 0.0;
  // iter 0: rows gw, gw+8448, gw+16896 (max 25343 < VN, all valid)
  {
    const int v0 = gw, v1 = gw + 8448, v2 = gw + 16896;
    const float4* r0 = ow4 + (size_t)v0 * 256;
    const float4* r1 = ow4 + (size_t)v1 * 256;
    const float4* r2 = ow4 + (size_t)v2 * 256;
    float a0 = dot4(r0[l], h0_) + dot4(r0[64 + l], h1_) +
               dot4(r0[128 + l], h2_) + dot4(r0[192 + l], h3_);
    float a1 = dot4(r1[l], h0_) + dot4(r1[64 + l], h1_) +
               dot4(r1[128 + l], h2_) + dot4(r1[192 + l], h3_);
    float a2 = dot4(r2[l], h0_) + dot4(r2[64 + l], h1_) +
               dot4(r2[128 + l], h2_) + dot4(r2[192 + l], h3_);
    a0 = wred(a0); a1 = wred(a1); a2 = wred(a2);
    if (l == 0) {
      float lg0 = a0 + out_b[v0];
      float lg1 = a1 + out_b[v1];
      float lg2 = a2 + out_b[v2];
      ws[WS_LOGITS + v0] = lg0;
      ws[WS_LOGITS + v1] = lg1;
      ws[WS_LOGITS + v2] = lg2;
      eacc += (double)expf(lg0) + (double)expf(lg1) + (double)expf(lg2);
    }
  }
  // iter 1: rows gw+25344, gw+33792, gw+42240 (third valid iff gw < 8017)
  {
    const int v0 = gw + 25344, v1 = gw + 33792, v2 = gw + 42240;
    const bool ok2 = (v2 < VN);  // wave-uniform
    const float4* r0 = ow4 + (size_t)v0 * 256;
    const float4* r1 = ow4 + (size_t)v1 * 256;
    const float4* r2 = ow4 + (size_t)(ok2 ? v2 : v1) * 256;  // clamp: in-bounds
    float a0 = dot4(r0[l], h0_) + dot4(r0[64 + l], h1_) +
               dot4(r0[128 + l], h2_) + dot4(r0[192 + l], h3_);
    float a1 = dot4(r1[l], h0_) + dot4(r1[64 + l], h1_) +
               dot4(r1[128 + l], h2_) + dot4(r1[192 + l], h3_);
    float a2 = dot4(r2[l], h0_) + dot4(r2[64 + l], h1_) +
               dot4(r2[128 + l], h2_) + dot4(r2[192 + l], h3_);
    a0 = wred(a0); a1 = wred(a1); a2 = wred(a2);
    if (l == 0) {
      float lg0 = a0 + out_b[v0];
      float lg1 = a1 + out_b[v1];
      ws[WS_LOGITS + v0] = lg0;
      ws[WS_LOGITS + v1] = lg1;
      eacc += (double)expf(lg0) + (double)expf(lg1);
      if (ok2) {
        float lg2 = a2 + out_b[v2];
        ws[WS_LOGITS + v2] = lg2;
        eacc += (double)expf(lg2);
      }
    }
  }
  __shared__ double sd[4];
  if (l == 0) sd[w] = eacc;
  __syncthreads();
  if (t == 0) ((double*)(ws + WS_EXPD))[blk] = sd[0] + sd[1] + sd[2] + sd[3];
}

// K6: redundant deterministic logZ (fixed-order reduce of 2112 doubles) + subtract
__global__ void k6_final(const float* __restrict__ ws, float* __restrict__ d_out) {
  __shared__ double sd[256];
  const int t = threadIdx.x;
  const double* ed = (const double*)(ws + WS_EXPD);
  double a = 0.0;
#pragma unroll
  for (int j = 0; j < 8; ++j) a += ed[t + j * 256];
  if (t < 64) a += ed[t + 2048];
  sd[t] = a;
  __syncthreads();
  for (int s = 128; s; s >>= 1) {
    if (t < s) sd[t] += sd[t + s];
    __syncthreads();
  }
  const float logZ = (float)log(sd[0]);
  const int v = blockIdx.x * 256 + t;
  if (v < VN) d_out[v] = ws[WS_LOGITS + v] - logZ;
}

extern "C" void kernel_launch(void* const* d_in, const int* in_sizes, int n_in,
                              void* d_out, int out_size, void* d_ws, size_t ws_size,
                              hipStream_t stream) {
  const int* token = (const int*)d_in[0];
  const float* hidden = (const float*)d_in[1];
  const float* enc = (const float*)d_in[2];
  const float* embedding = (const float*)d_in[3];
  // d_in[4] attn_w, d_in[5] attn_b unused: softmax(broadcast(scalar)) is uniform
  const float* comb_w = (const float*)d_in[6];
  const float* comb_b = (const float*)d_in[7];
  const float* w_ih = (const float*)d_in[8];
  const float* w_hh = (const float*)d_in[9];
  const float* b_ih = (const float*)d_in[10];
  const float* b_hh = (const float*)d_in[11];
  const float* out_w = (const float*)d_in[12];
  const float* out_b = (const float*)d_in[13];
  float* out = (float*)d_out;
  float* ws = (float*)d_ws;

  k1_front<<<256, 1024, 0, stream>>>(enc, w_hh, hidden, token, embedding,
                                     comb_w, comb_b, ws, out + VN + HN);
  k2_reduce<<<32, 1024, 0, stream>>>(ws);
  k3_x<<<256, 256, 0, stream>>>(comb_w, ws);
  k4_gates_h<<<256, 256, 0, stream>>>(w_ih, b_ih, b_hh, hidden, ws, out);
  k5_logits<<<2112, 256, 0, stream>>>(out_w, out_b, ws);
  k6_final<<<197, 256, 0, stream>>>(ws, out);
}

// Round 9
// 57.925 us; speedup vs baseline: 1.7273x; 1.0040x over previous
//
#include <hip/hip_runtime.h>
#include <math.h>

#define HN 1024
#define VN 50257
#define SN 8192

// ws layout (float offsets)
#define WS_PARTIAL 0          // 8*1024: per-rowchunk column partial sums
#define WS_X       8192       // 1024: relu(combined)
#define WS_GH      9216       // 3072: raw w_hh @ h0
#define WS_CEMB    12288      // 1024: comb_w[:, :H] @ emb + comb_b
#define WS_HNEW    13312      // 1024: h_new
#define WS_LOGITS  14336      // 50257
#define WS_EXPD    64594      // 2112 doubles (8B-aligned: 64594*4 % 8 == 0)

__device__ __forceinline__ float wred(float v) {
#pragma unroll
  for (int m = 32; m; m >>= 1) v += __shfl_xor(v, m);
  return v;
}

__device__ __forceinline__ float dot4(float4 a, float4 b) {
  return a.x * b.x + a.y * b.y + a.z * b.z + a.w * b.w;
}

// K1 (256 blocks x 1024 thr), uniform ~136 KB/block:
//   phase A: column partial over rows [chunk*1024, +1024), cols [stripe*32, +32)
//            (chunk = blk>>5, stripe = blk&31; 128B-aligned stripe lines)
//            -> partial[chunk][stripe*32+c]; + 32 attn_weights elements
//   phase B: waves 0-3: cemb rows blk*4+w = comb_w[i, :H] @ emb + comb_b[i]
__global__ __launch_bounds__(1024) void k1_front(
    const float* __restrict__ enc, const int* __restrict__ token,
    const float* __restrict__ embedding, const float* __restrict__ comb_w,
    const float* __restrict__ comb_b, float* __restrict__ ws,
    float* __restrict__ out_attn) {
  const int blk = blockIdx.x, t = threadIdx.x;
  __shared__ float lds[1024];
  const int chunk = blk >> 5, stripe = blk & 31;
  {
    const float* base =
        enc + ((size_t)chunk * 1024 + (t >> 5)) * 1024 + stripe * 32 + (t & 31);
    float s = 0.f;
#pragma unroll 8
    for (int j = 0; j < 32; ++j) s += base[j * 32768];  // 32-row stride
    lds[t] = s;
  }
  __syncthreads();
  if (t < 32) {
    float a = 0.f;
#pragma unroll
    for (int j = 0; j < 32; ++j) a += lds[t + j * 32];
    ws[WS_PARTIAL + chunk * 1024 + stripe * 32 + t] = a;
    out_attn[blk * 32 + t] = 1.f / 8192.f;  // softmax(const) == uniform, exact
  }
  const int w = t >> 6, l = t & 63;
  if (w < 4) {
    const int i = blk * 4 + w;  // 0..1023
    const int tok = token[0];
    const float4* emb4 = (const float4*)embedding + (size_t)tok * 256;
    const float4* cw4 = (const float4*)comb_w + (size_t)i * 512;  // first half
    float acc = dot4(cw4[l], emb4[l]) + dot4(cw4[64 + l], emb4[64 + l]) +
                dot4(cw4[128 + l], emb4[128 + l]) + dot4(cw4[192 + l], emb4[192 + l]);
    acc = wred(acc);
    if (l == 0) ws[WS_CEMB + i] = acc + comb_b[i];
  }
}

// K2 (256 blocks x 1024): block-specialized:
//   blk<192 : gh row r = blk*16 + w  (one 4KB row per wave)
//   192..255: x rows — block redundantly reduces the 8 column-partials
//             (32 KB L2) into LDS aa, then 16 waves each do one row:
//             x[i] = relu(cemb[i] + comb_w[i, H:] @ aa)
__global__ __launch_bounds__(1024) void k2_mid(
    const float* __restrict__ w_hh, const float* __restrict__ hidden,
    const float* __restrict__ comb_w, float* __restrict__ ws) {
  const int blk = blockIdx.x, t = threadIdx.x;
  const int w = t >> 6, l = t & 63;
  if (blk < 192) {
    const int r = blk * 16 + w;  // 0..3071
    const float4* h4 = (const float4*)hidden;
    const float4* m4 = (const float4*)w_hh + (size_t)r * 256;
    float acc = dot4(m4[l], h4[l]) + dot4(m4[64 + l], h4[64 + l]) +
                dot4(m4[128 + l], h4[128 + l]) + dot4(m4[192 + l], h4[192 + l]);
    acc = wred(acc);
    if (l == 0) ws[WS_GH + r] = acc;
  } else {
    __shared__ float aas[1024];
    float s = 0.f;
#pragma unroll
    for (int j = 0; j < 8; ++j) s += ws[WS_PARTIAL + j * 1024 + t];
    aas[t] = s * (1.f / 8192.f);
    __syncthreads();
    const int i = (blk - 192) * 16 + w;  // 0..1023
    const float4* aa4 = (const float4*)aas;
    const float4* cw4 = (const float4*)comb_w + (size_t)i * 512 + 256;  // 2nd half
    float acc = dot4(cw4[l], aa4[l]) + dot4(cw4[64 + l], aa4[64 + l]) +
                dot4(cw4[128 + l], aa4[128 + l]) + dot4(cw4[192 + l], aa4[192 + l]);
    acc = wred(acc);
    if (l == 0) ws[WS_X + i] = fmaxf(ws[WS_CEMB + i] + acc, 0.f);
  }
}

// K4 (256 blocks x 256): wave computes all 3 gi rows for its i, then lane 0
// applies GRU gate math -> h_new.
__global__ void k4_gates_h(const float* __restrict__ w_ih,
                           const float* __restrict__ b_ih, const float* __restrict__ b_hh,
                           const float* __restrict__ hidden, float* __restrict__ ws,
                           float* __restrict__ d_out) {
  const int w = threadIdx.x >> 6, l = threadIdx.x & 63;
  const int i = blockIdx.x * 4 + w;  // 0..1023
  const float4* x4 = (const float4*)(ws + WS_X);
  float4 xv0 = x4[l], xv1 = x4[64 + l], xv2 = x4[128 + l], xv3 = x4[192 + l];
  const float4* m0 = (const float4*)w_ih + (size_t)i * 256;
  const float4* m1 = (const float4*)w_ih + (size_t)(i + 1024) * 256;
  const float4* m2 = (const float4*)w_ih + (size_t)(i + 2048) * 256;
  float a0 = dot4(m0[l], xv0) + dot4(m0[64 + l], xv1) +
             dot4(m0[128 + l], xv2) + dot4(m0[192 + l], xv3);
  float a1 = dot4(m1[l], xv0) + dot4(m1[64 + l], xv1) +
             dot4(m1[128 + l], xv2) + dot4(m1[192 + l], xv3);
  float a2 = dot4(m2[l], xv0) + dot4(m2[64 + l], xv1) +
             dot4(m2[128 + l], xv2) + dot4(m2[192 + l], xv3);
  a0 = wred(a0); a1 = wred(a1); a2 = wred(a2);
  if (l == 0) {
    float ir = a0 + b_ih[i];
    float iz = a1 + b_ih[i + 1024];
    float inn = a2 + b_ih[i + 2048];
    float hr = ws[WS_GH + i] + b_hh[i];
    float hz = ws[WS_GH + i + 1024] + b_hh[i + 1024];
    float hn = ws[WS_GH + i + 2048] + b_hh[i + 2048];
    float rg = 1.f / (1.f + expf(-(ir + hr)));
    float zg = 1.f / (1.f + expf(-(iz + hz)));
    float ng = tanhf(inn + rg * hn);
    float h = (1.f - zg) * ng + zg * hidden[i];
    ws[WS_HNEW + i] = h;
    d_out[VN + i] = h;  // h_new output region
  }
}

// K5 (2112 blocks x 256 = 8448 waves): logits GEMV, 2 iters x 3-row ILP,
// every wave <= 6 rows. Per-block exp partials in fixed order (deterministic).
__global__ void k5_logits(const float* __restrict__ out_w, const float* __restrict__ out_b,
                          float* __restrict__ ws) {
  const int blk = blockIdx.x, t = threadIdx.x;
  const int w = t >> 6, l = t & 63;
  const int gw = blk * 4 + w;  // 0..8447
  const float4* h4p = (const float4*)(ws + WS_HNEW);
  float4 h0_ = h4p[l], h1_ = h4p[64 + l], h2_ = h4p[128 + l], h3_ = h4p[192 + l];
  const float4* ow4 = (const float4*)out_w;
  double eacc = 0.0;
  // iter 0: rows gw, gw+8448, gw+16896 (max 25343 < VN, all valid)
  {
    const int v0 = gw, v1 = gw + 8448, v2 = gw + 16896;
    const float4* r0 = ow4 + (size_t)v0 * 256;
    const float4* r1 = ow4 + (size_t)v1 * 256;
    const float4* r2 = ow4 + (size_t)v2 * 256;
    float a0 = dot4(r0[l], h0_) + dot4(r0[64 + l], h1_) +
               dot4(r0[128 + l], h2_) + dot4(r0[192 + l], h3_);
    float a1 = dot4(r1[l], h0_) + dot4(r1[64 + l], h1_) +
               dot4(r1[128 + l], h2_) + dot4(r1[192 + l], h3_);
    float a2 = dot4(r2[l], h0_) + dot4(r2[64 + l], h1_) +
               dot4(r2[128 + l], h2_) + dot4(r2[192 + l], h3_);
    a0 = wred(a0); a1 = wred(a1); a2 = wred(a2);
    if (l == 0) {
      float lg0 = a0 + out_b[v0];
      float lg1 = a1 + out_b[v1];
      float lg2 = a2 + out_b[v2];
      ws[WS_LOGITS + v0] = lg0;
      ws[WS_LOGITS + v1] = lg1;
      ws[WS_LOGITS + v2] = lg2;
      eacc += (double)expf(lg0) + (double)expf(lg1) + (double)expf(lg2);
    }
  }
  // iter 1: rows gw+25344, gw+33792, gw+42240 (third valid iff gw < 8017)
  {
    const int v0 = gw + 25344, v1 = gw + 33792, v2 = gw + 42240;
    const bool ok2 = (v2 < VN);  // wave-uniform
    const float4* r0 = ow4 + (size_t)v0 * 256;
    const float4* r1 = ow4 + (size_t)v1 * 256;
    const float4* r2 = ow4 + (size_t)(ok2 ? v2 : v1) * 256;  // clamp: in-bounds
    float a0 = dot4(r0[l], h0_) + dot4(r0[64 + l], h1_) +
               dot4(r0[128 + l], h2_) + dot4(r0[192 + l], h3_);
    float a1 = dot4(r1[l], h0_) + dot4(r1[64 + l], h1_) +
               dot4(r1[128 + l], h2_) + dot4(r1[192 + l], h3_);
    float a2 = dot4(r2[l], h0_) + dot4(r2[64 + l], h1_) +
               dot4(r2[128 + l], h2_) + dot4(r2[192 + l], h3_);
    a0 = wred(a0); a1 = wred(a1); a2 = wred(a2);
    if (l == 0) {
      float lg0 = a0 + out_b[v0];
      float lg1 = a1 + out_b[v1];
      ws[WS_LOGITS + v0] = lg0;
      ws[WS_LOGITS + v1] = lg1;
      eacc += (double)expf(lg0) + (double)expf(lg1);
      if (ok2) {
        float lg2 = a2 + out_b[v2];
        ws[WS_LOGITS + v2] = lg2;
        eacc += (double)expf(lg2);
      }
    }
  }
  __shared__ double sd[4];
  if (l == 0) sd[w] = eacc;
  __syncthreads();
  if (t == 0) ((double*)(ws + WS_EXPD))[blk] = sd[0] + sd[1] + sd[2] + sd[3];
}

// K6: redundant deterministic logZ (fixed-order reduce of 2112 doubles) + subtract
__global__ void k6_final(const float* __restrict__ ws, float* __restrict__ d_out) {
  __shared__ double sd[256];
  const int t = threadIdx.x;
  const double* ed = (const double*)(ws + WS_EXPD);
  double a = 0.0;
#pragma unroll
  for (int j = 0; j < 8; ++j) a += ed[t + j * 256];
  if (t < 64) a += ed[t + 2048];
  sd[t] = a;
  __syncthreads();
  for (int s = 128; s; s >>= 1) {
    if (t < s) sd[t] += sd[t + s];
    __syncthreads();
  }
  const float logZ = (float)log(sd[0]);
  const int v = blockIdx.x * 256 + t;
  if (v < VN) d_out[v] = ws[WS_LOGITS + v] - logZ;
}

extern "C" void kernel_launch(void* const* d_in, const int* in_sizes, int n_in,
                              void* d_out, int out_size, void* d_ws, size_t ws_size,
                              hipStream_t stream) {
  const int* token = (const int*)d_in[0];
  const float* hidden = (const float*)d_in[1];
  const float* enc = (const float*)d_in[2];
  const float* embedding = (const float*)d_in[3];
  // d_in[4] attn_w, d_in[5] attn_b unused: softmax(broadcast(scalar)) is uniform
  const float* comb_w = (const float*)d_in[6];
  const float* comb_b = (const float*)d_in[7];
  const float* w_ih = (const float*)d_in[8];
  const float* w_hh = (const float*)d_in[9];
  const float* b_ih = (const float*)d_in[10];
  const float* b_hh = (const float*)d_in[11];
  const float* out_w = (const float*)d_in[12];
  const float* out_b = (const float*)d_in[13];
  float* out = (float*)d_out;
  float* ws = (float*)d_ws;

  k1_front<<<256, 1024, 0, stream>>>(enc, token, embedding, comb_w, comb_b,
                                     ws, out + VN + HN);
  k2_mid<<<256, 1024, 0, stream>>>(w_hh, hidden, comb_w, ws);
  k4_gates_h<<<256, 256, 0, stream>>>(w_ih, b_ih, b_hh, hidden, ws, out);
  k5_logits<<<2112, 256, 0, stream>>>(out_w, out_b, ws);
  k6_final<<<197, 256, 0, stream>>>(ws, out);
}